// Round 4
// baseline (272.999 us; speedup 1.0000x reference)
//
#include <hip/hip_runtime.h>
#include <stdint.h>

// Problem constants (fixed by setup_inputs)
constexpr int B_SZ     = 128;
constexpr int IN_CAPS  = 1152;
constexpr int OUT_CAPS = 32;
constexpr int IN_D     = 8;
constexpr int OUT_D    = 16;
constexpr int ITERS    = 3;

constexpr int THREADS  = 768;               // 12 waves
constexpr int NW       = THREADS / 64;      // 12
constexpr int G        = 2;                 // batches per block
constexpr int TILE_R   = 192;               // i-rows per LDS tile
constexpr int NTILE    = IN_CAPS / TILE_R;  // 6
constexpr int ROW_U32  = 64;                // 128 bf16 = 256 B per row
constexpr int W_ISTRIDE = OUT_CAPS * IN_D * OUT_D;  // 4096 floats between i's

// One block per (j, batch-pair). Thread owns (bl = which batch, mh = which
// half of m, ir = i-row within tile): uh[6][8] = 48 VGPRs. Weight column
// w[:,j,:,:] streams through double-buffered bf16 LDS tiles (2 x 48 KB).
//
// R2/R3 lesson: the backend targeted 6 waves/EU on its own (VGPR_Count=84)
// and spilled uh/stg to scratch (400+ MB of WRITE_SIZE). LDS=100KB caps us
// at 1 block/CU = 3 waves/EU regardless, so pin the allocator there:
// amdgpu_waves_per_eu(3,3) -> ~170-VGPR budget, no spill.
// Tile steps are macro-expanded with literal indices (rule #20 insurance).
__global__
__attribute__((amdgpu_flat_work_group_size(THREADS, THREADS)))
__attribute__((amdgpu_waves_per_eu(3, 3)))
void caps_route(
    const float* __restrict__ u,   // [B, IN_CAPS, IN_D]
    const float* __restrict__ w,   // [IN_CAPS, OUT_CAPS, IN_D, OUT_D]
    float* __restrict__ out)       // [B, OUT_CAPS, OUT_D]
{
    __shared__ __align__(16) uint32_t tile[2][TILE_R * ROW_U32]; // 96 KB
    __shared__ float red_s[NW * 4];          // esum partials per (wave,grp)
    __shared__ float red_m[NW * 4 * 8];      // s[8] partials
    __shared__ float red_s2[4];              // s^2 halves exchange

    // Bijective XCD swizzle (2048 % 8 == 0): j-major ids -> each XCD's L2
    // holds 4 j-columns (2.3 MB).
    const int nwg = gridDim.x;               // 2048
    const int bid = blockIdx.x;
    const int wid = (bid & 7) * (nwg >> 3) + (bid >> 3);
    const int j   = wid >> 6;                // 0..31
    const int b0  = (wid & 63) * G;          // 0..126 step 2

    const int tid  = threadIdx.x;
    const int bl   = tid & 1;                // batch within pair
    const int mh   = (tid >> 1) & 1;         // m-half (m = mh*8 + k)
    const int ir   = tid >> 2;               // i-row in tile, 0..191
    const int wv   = tid >> 6;               // wave 0..11
    const int lane = tid & 63;
    const int b    = b0 + bl;
    const int sz   = ir & 15;                // read-side swizzle

    // staging mapping: float4 index = q*768+tid -> (row, col)
    const int srow = tid >> 5;               // 0..23
    const int sc4  = tid & 31;               // float4 within row
    const int so   = sc4 >> 1;               // 16B slot 0..15
    const int sh   = sc4 & 1;                // half of slot

    const float* wj = w + (size_t)j * (IN_D * OUT_D);

    float uh[NTILE][8];                      // 48 VGPRs, literal indexing only
    float unA[8], unB[8];                    // u for current/next tile
    float4 stg[8];                           // in-flight weight float4s

    // ---- prologue: stage tile 0, load unA ----
    #pragma unroll
    for (int q = 0; q < 8; ++q)
        stg[q] = *reinterpret_cast<const float4*>(
            wj + (size_t)(q * 24 + srow) * W_ISTRIDE + sc4 * 4);
    {
        const float4 ua = *reinterpret_cast<const float4*>(
            u + ((size_t)b * IN_CAPS + ir) * IN_D);
        const float4 ub = *reinterpret_cast<const float4*>(
            u + ((size_t)b * IN_CAPS + ir) * IN_D + 4);
        unA[0]=ua.x; unA[1]=ua.y; unA[2]=ua.z; unA[3]=ua.w;
        unA[4]=ub.x; unA[5]=ub.y; unA[6]=ub.z; unA[7]=ub.w;
    }
    #pragma unroll
    for (int q = 0; q < 8; ++q) {
        const int row = q * 24 + srow;
        uint32_t p0, p1;
        asm("v_cvt_pk_bf16_f32 %0, %1, %2" : "=v"(p0) : "v"(stg[q].x), "v"(stg[q].y));
        asm("v_cvt_pk_bf16_f32 %0, %1, %2" : "=v"(p1) : "v"(stg[q].z), "v"(stg[q].w));
        *reinterpret_cast<uint2*>(
            &tile[0][row * ROW_U32 + ((so ^ (row & 15)) << 2) + (sh << 1)]) =
            make_uint2(p0, p1);
    }
    __syncthreads();

    // ---- tile step T: issue(T+1) | compute(T) | commit(T+1) | barrier ----
    // All array indices are literals after macro expansion.
    #define TILE_STEP(T, UC, UN)                                              \
    do {                                                                      \
        if ((T) < NTILE - 1) {                                                \
            _Pragma("unroll")                                                 \
            for (int q = 0; q < 8; ++q)                                       \
                stg[q] = *reinterpret_cast<const float4*>(                    \
                    wj + (size_t)(((T) + 1) * TILE_R + q * 24 + srow) *       \
                             W_ISTRIDE + sc4 * 4);                            \
            const float4 ua = *reinterpret_cast<const float4*>(               \
                u + ((size_t)b * IN_CAPS + ((T) + 1) * TILE_R + ir) * IN_D);  \
            const float4 ub = *reinterpret_cast<const float4*>(               \
                u + ((size_t)b * IN_CAPS + ((T) + 1) * TILE_R + ir) * IN_D + 4); \
            UN[0]=ua.x; UN[1]=ua.y; UN[2]=ua.z; UN[3]=ua.w;                   \
            UN[4]=ub.x; UN[5]=ub.y; UN[6]=ub.z; UN[7]=ub.w;                   \
        }                                                                     \
        {                                                                     \
            const uint32_t* trow = &tile[(T) & 1][ir * ROW_U32];              \
            _Pragma("unroll")                                                 \
            for (int k = 0; k < 8; ++k) uh[(T)][k] = 0.0f;                    \
            _Pragma("unroll")                                                 \
            for (int n = 0; n < IN_D; ++n) {                                  \
                const uint4 rd = *reinterpret_cast<const uint4*>(             \
                    &trow[((2 * n + mh) ^ sz) << 2]);                         \
                const float uvn = UC[n];                                      \
                uh[(T)][0] = fmaf(uvn, __uint_as_float(rd.x << 16),        uh[(T)][0]); \
                uh[(T)][1] = fmaf(uvn, __uint_as_float(rd.x & 0xffff0000u), uh[(T)][1]); \
                uh[(T)][2] = fmaf(uvn, __uint_as_float(rd.y << 16),        uh[(T)][2]); \
                uh[(T)][3] = fmaf(uvn, __uint_as_float(rd.y & 0xffff0000u), uh[(T)][3]); \
                uh[(T)][4] = fmaf(uvn, __uint_as_float(rd.z << 16),        uh[(T)][4]); \
                uh[(T)][5] = fmaf(uvn, __uint_as_float(rd.z & 0xffff0000u), uh[(T)][5]); \
                uh[(T)][6] = fmaf(uvn, __uint_as_float(rd.w << 16),        uh[(T)][6]); \
                uh[(T)][7] = fmaf(uvn, __uint_as_float(rd.w & 0xffff0000u), uh[(T)][7]); \
            }                                                                 \
        }                                                                     \
        if ((T) < NTILE - 1) {                                                \
            _Pragma("unroll")                                                 \
            for (int q = 0; q < 8; ++q) {                                     \
                const int row = q * 24 + srow;                                \
                uint32_t p0, p1;                                              \
                asm("v_cvt_pk_bf16_f32 %0, %1, %2" : "=v"(p0) : "v"(stg[q].x), "v"(stg[q].y)); \
                asm("v_cvt_pk_bf16_f32 %0, %1, %2" : "=v"(p1) : "v"(stg[q].z), "v"(stg[q].w)); \
                *reinterpret_cast<uint2*>(                                    \
                    &tile[((T) + 1) & 1][row * ROW_U32 +                      \
                        ((so ^ (row & 15)) << 2) + (sh << 1)]) =              \
                    make_uint2(p0, p1);                                       \
            }                                                                 \
        }                                                                     \
        __syncthreads();                                                      \
    } while (0)

    TILE_STEP(0, unA, unB);
    TILE_STEP(1, unB, unA);
    TILE_STEP(2, unA, unB);
    TILE_STEP(3, unB, unA);
    TILE_STEP(4, unA, unB);
    TILE_STEP(5, unB, unA);
    #undef TILE_STEP

    // ---- routing iterations ----
    float blog[NTILE];
    #pragma unroll
    for (int r = 0; r < NTILE; ++r) blog[r] = 0.0f;
    float vv[8];
    const int grp = lane & 3;                // (mh<<1)|bl

    for (int it = 0; it < ITERS; ++it) {
        // softmax denominator over i for my b (iter 0: exp(0)=1 exactly;
        // logits stay small; no max-subtraction needed in f32)
        float e[NTILE];
        float esum = 0.0f;
        #pragma unroll
        for (int r = 0; r < NTILE; ++r) { e[r] = __expf(blog[r]); esum += e[r]; }
        #pragma unroll
        for (int msk = 4; msk <= 32; msk <<= 1) esum += __shfl_xor(esum, msk);
        if (lane < 4) red_s[wv * 4 + lane] = esum;
        __syncthreads();
        float gsum = 0.0f;
        #pragma unroll
        for (int q = 0; q < NW; ++q) gsum += red_s[q * 4 + grp];
        const float cinv = 1.0f / gsum;

        // s[k] (my m-half) = cinv * sum_i e_i * uh[i][k]
        float sp[8];
        #pragma unroll
        for (int k = 0; k < 8; ++k) sp[k] = 0.0f;
        #pragma unroll
        for (int r = 0; r < NTILE; ++r)
            #pragma unroll
            for (int k = 0; k < 8; ++k)
                sp[k] = fmaf(e[r], uh[r][k], sp[k]);
        #pragma unroll
        for (int msk = 4; msk <= 32; msk <<= 1)
            #pragma unroll
            for (int k = 0; k < 8; ++k)
                sp[k] += __shfl_xor(sp[k], msk);
        if (lane < 4) {
            #pragma unroll
            for (int k = 0; k < 8; ++k) red_m[(wv * 4 + lane) * 8 + k] = sp[k];
        }
        __syncthreads();
        float s2p = 0.0f;
        #pragma unroll
        for (int k = 0; k < 8; ++k) {
            float acc = 0.0f;
            #pragma unroll
            for (int q = 0; q < NW; ++q) acc += red_m[(q * 4 + grp) * 8 + k];
            const float sm = acc * cinv;
            vv[k] = sm;
            s2p = fmaf(sm, sm, s2p);
        }
        if (tid < 4) red_s2[tid] = s2p;      // tid<4 <=> wv==0, ir==0
        __syncthreads();
        const float s2 = red_s2[bl] + red_s2[2 + bl];   // both m-halves
        const float scale = (s2 / (1.0f + s2)) * rsqrtf(s2 + 1e-8f);
        #pragma unroll
        for (int k = 0; k < 8; ++k) vv[k] *= scale;

        // logit update: partner (mask 2) holds the other m-half of (b, i)
        if (it < ITERS - 1) {
            #pragma unroll
            for (int r = 0; r < NTILE; ++r) {
                float a = 0.0f;
                #pragma unroll
                for (int k = 0; k < 8; ++k) a = fmaf(vv[k], uh[r][k], a);
                a += __shfl_xor(a, 2);
                blog[r] += a;
            }
        }
    }

    // ---- write v[b0+bl, j, mh*8 .. mh*8+7] ----
    if (tid < 4) {
        float4* op = reinterpret_cast<float4*>(
            out + ((size_t)(b0 + bl) * OUT_CAPS + j) * OUT_D + mh * 8);
        op[0] = make_float4(vv[0], vv[1], vv[2], vv[3]);
        op[1] = make_float4(vv[4], vv[5], vv[6], vv[7]);
    }
}

extern "C" void kernel_launch(void* const* d_in, const int* in_sizes, int n_in,
                              void* d_out, int out_size, void* d_ws, size_t ws_size,
                              hipStream_t stream) {
    const float* u = (const float*)d_in[0];   // [128, 1152, 8]
    const float* w = (const float*)d_in[1];   // [1152, 32, 8, 16]
    float* out     = (float*)d_out;           // [128, 32, 16]
    (void)in_sizes; (void)n_in; (void)out_size; (void)d_ws; (void)ws_size;

    dim3 grid(OUT_CAPS * (B_SZ / G));   // 32 j x 64 batch-pairs = 2048 blocks
    dim3 block(THREADS);                // 768 threads = 12 waves
    hipLaunchKernelGGL(caps_route, grid, block, 0, stream, u, w, out);
}

// Round 5
// 158.006 us; speedup vs baseline: 1.7278x; 1.7278x over previous
//
#include <hip/hip_runtime.h>
#include <stdint.h>

// Problem constants (fixed by setup_inputs)
constexpr int B_SZ     = 128;
constexpr int IN_CAPS  = 1152;
constexpr int OUT_CAPS = 32;
constexpr int IN_D     = 8;
constexpr int OUT_D    = 16;
constexpr int ITERS    = 3;

constexpr int THREADS  = 1024;              // 16 waves
constexpr int NW       = THREADS / 64;      // 16
constexpr int G        = 2;                 // batches per block
constexpr int TILE_R   = 128;               // i-rows per LDS tile
constexpr int NTILE    = IN_CAPS / TILE_R;  // 9
constexpr int ROW_F    = 128;               // f32 per weight row (32 x 16B chunks)

// async global->LDS, 16B per lane, dest = wave-uniform base + lane*16
typedef const uint32_t __attribute__((address_space(1)))* gptr_t;
typedef uint32_t       __attribute__((address_space(3)))* lptr_t;
__device__ __forceinline__ void async_copy16(const float* g, float* l) {
    __builtin_amdgcn_global_load_lds((gptr_t)g, (lptr_t)l, 16, 0, 0);
}

// One block per (j, batch-pair). Thread = (bl = batch, mq = m-quarter,
// ir = i-row): uh[9][4] = 36 VGPRs. Weight column w[:,j,:,:] streams f32
// through double-buffered LDS tiles via global_load_lds (zero staging regs).
// R2-R4 lesson: the allocator pins ~84 VGPRs regardless of hints; peak live
// state here is ~72 so nothing can spill.
//
// Swizzle (rule #21, both-sides): global_load_lds writes LDS linearly, so the
// GLOBAL source chunk is pre-permuted: LDS[row][slot] = G[row][slot ^ m(row)],
// m(row) = (row&7)|((row&3)<<3). Reads use the same involution. This makes the
// 32 unique ds_read_b128 addresses per instruction hit 32 distinct 16B
// slot-columns -> every bank-quad serves exactly 4 addrs = data-limited min.
__global__ __launch_bounds__(THREADS) void caps_route(
    const float* __restrict__ u,   // [B, IN_CAPS, IN_D]
    const float* __restrict__ w,   // [IN_CAPS, OUT_CAPS, IN_D, OUT_D]
    float* __restrict__ out)       // [B, OUT_CAPS, OUT_D]
{
    __shared__ __align__(16) float tile[2][TILE_R * ROW_F];  // 2 x 64 KB
    __shared__ float red_es[NW * 8];                         // esum partials
    __shared__ __align__(16) float red_m[NW * 8 * 4];        // s[4] partials

    // Bijective XCD swizzle (2048 % 8 == 0): j-major ids -> each XCD's L2
    // holds 4 j-columns (2.3 MB < 4 MB).
    const int nwg = gridDim.x;               // 2048
    const int bid = blockIdx.x;
    const int wid = (bid & 7) * (nwg >> 3) + (bid >> 3);
    const int j   = wid >> 6;                // 0..31
    const int b0  = (wid & 63) * G;          // 0..126 step 2

    const int tid  = threadIdx.x;
    const int lane = tid & 63;
    const int wv   = tid >> 6;               // wave 0..15
    const int bl   = tid & 1;                // batch within pair
    const int mq   = (tid >> 1) & 3;         // m-quarter (m = mq*4 + k)
    const int ir   = tid >> 3;               // i-row in tile, 0..127
    const int b    = b0 + bl;

    // read-side swizzled chunk offsets (tile-invariant): float index of the
    // 16B chunk holding (n, m=mq*4..mq*4+3) after the XOR permutation
    const int mir = (ir & 7) | ((ir & 3) << 3);
    int foff[8];
    #pragma unroll
    for (int n = 0; n < 8; ++n) foff[n] = (((4 * n + mq) ^ mir) << 2);

    float uh[NTILE][4];                      // 36 VGPRs, literal indexing
    float4 uA0, uA1, uB0, uB1;               // u[b, i, :] cur/next tile

    // stage weight tile T into LDS buffer NB (4 x 1KB wave-issues)
    #define STAGE_TILE(NB, T)                                                 \
    do {                                                                      \
        _Pragma("unroll")                                                     \
        for (int q = 0; q < 4; ++q) {                                         \
            const int Lb   = (wv * 4 + q) * 64;    /* chunk base, uniform */  \
            const int L    = Lb + lane;                                       \
            const int row  = L >> 5;                                          \
            const int slot = L & 31;                                          \
            const int c    = slot ^ ((row & 7) | ((row & 3) << 3));           \
            const float* gsrc = w +                                           \
                ((size_t)(((T) * TILE_R + row) * OUT_CAPS + j) * ROW_F + c * 4); \
            async_copy16(gsrc, &tile[(NB)][Lb * 4]);                          \
        }                                                                     \
    } while (0)

    // compute uh[T][0..3] from LDS buffer NB using u regs UC0/UC1
    #define COMP_TILE(NB, T, UC0, UC1)                                        \
    do {                                                                      \
        const float* trow = &tile[(NB)][ir * ROW_F];                          \
        const float uc[8] = {UC0.x, UC0.y, UC0.z, UC0.w,                      \
                             UC1.x, UC1.y, UC1.z, UC1.w};                     \
        float4 acc = make_float4(0.f, 0.f, 0.f, 0.f);                         \
        _Pragma("unroll")                                                     \
        for (int n = 0; n < 8; ++n) {                                         \
            const float4 w4 = *reinterpret_cast<const float4*>(trow + foff[n]); \
            acc.x = fmaf(uc[n], w4.x, acc.x);                                 \
            acc.y = fmaf(uc[n], w4.y, acc.y);                                 \
            acc.z = fmaf(uc[n], w4.z, acc.z);                                 \
            acc.w = fmaf(uc[n], w4.w, acc.w);                                 \
        }                                                                     \
        uh[(T)][0] = acc.x; uh[(T)][1] = acc.y;                               \
        uh[(T)][2] = acc.z; uh[(T)][3] = acc.w;                               \
    } while (0)

    // step T: issue stage(T+1) + u-prefetch(T+1), compute(T), barrier.
    // __syncthreads drains vmcnt(0) -> stage(T+1) complete for next step;
    // barrier also protects buffer (T+1)&1 from overwrite-before-read.
    #define STEP(T, UC0, UC1, UN0, UN1)                                       \
    do {                                                                      \
        if ((T) + 1 < NTILE) {                                                \
            STAGE_TILE(((T) + 1) & 1, (T) + 1);                               \
            const float* up = u +                                             \
                ((size_t)b * IN_CAPS + ((T) + 1) * TILE_R + ir) * IN_D;       \
            UN0 = *reinterpret_cast<const float4*>(up);                       \
            UN1 = *reinterpret_cast<const float4*>(up + 4);                   \
        }                                                                     \
        COMP_TILE((T) & 1, T, UC0, UC1);                                      \
        __syncthreads();                                                      \
    } while (0)

    // ---- prologue: stage tile 0, load u(0) ----
    STAGE_TILE(0, 0);
    {
        const float* up = u + ((size_t)b * IN_CAPS + ir) * IN_D;
        uA0 = *reinterpret_cast<const float4*>(up);
        uA1 = *reinterpret_cast<const float4*>(up + 4);
    }
    __syncthreads();

    STEP(0, uA0, uA1, uB0, uB1);
    STEP(1, uB0, uB1, uA0, uA1);
    STEP(2, uA0, uA1, uB0, uB1);
    STEP(3, uB0, uB1, uA0, uA1);
    STEP(4, uA0, uA1, uB0, uB1);
    STEP(5, uB0, uB1, uA0, uA1);
    STEP(6, uA0, uA1, uB0, uB1);
    STEP(7, uB0, uB1, uA0, uA1);
    STEP(8, uA0, uA1, uB0, uB1);
    #undef STEP
    #undef COMP_TILE
    #undef STAGE_TILE

    // ================= routing iterations =================
    float blog[NTILE];
    #pragma unroll
    for (int r = 0; r < NTILE; ++r) blog[r] = 0.0f;
    float vv[4];
    const int grp = lane & 7;                // (mq<<1)|bl

    for (int it = 0; it < ITERS; ++it) {
        // softmax denom over i for my b (iter 0: exp(0)=1 exactly; logits
        // stay small enough for f32 exp without max-subtraction — same as
        // the passing R3/R4 kernels)
        float e[NTILE];
        float esum = 0.0f;
        #pragma unroll
        for (int r = 0; r < NTILE; ++r) { e[r] = __expf(blog[r]); esum += e[r]; }
        esum += __shfl_xor(esum, 8);
        esum += __shfl_xor(esum, 16);
        esum += __shfl_xor(esum, 32);

        // s-partials for my m-quarter
        float sp0 = 0.f, sp1 = 0.f, sp2 = 0.f, sp3 = 0.f;
        #pragma unroll
        for (int r = 0; r < NTILE; ++r) {
            sp0 = fmaf(e[r], uh[r][0], sp0);
            sp1 = fmaf(e[r], uh[r][1], sp1);
            sp2 = fmaf(e[r], uh[r][2], sp2);
            sp3 = fmaf(e[r], uh[r][3], sp3);
        }
        sp0 += __shfl_xor(sp0, 8);  sp1 += __shfl_xor(sp1, 8);
        sp2 += __shfl_xor(sp2, 8);  sp3 += __shfl_xor(sp3, 8);
        sp0 += __shfl_xor(sp0, 16); sp1 += __shfl_xor(sp1, 16);
        sp2 += __shfl_xor(sp2, 16); sp3 += __shfl_xor(sp3, 16);
        sp0 += __shfl_xor(sp0, 32); sp1 += __shfl_xor(sp1, 32);
        sp2 += __shfl_xor(sp2, 32); sp3 += __shfl_xor(sp3, 32);

        if (lane < 8) {   // lane == (mq<<1)|bl, ir-group 0
            red_es[wv * 8 + lane] = esum;
            *reinterpret_cast<float4*>(&red_m[(wv * 8 + lane) * 4]) =
                make_float4(sp0, sp1, sp2, sp3);
        }
        __syncthreads();
        float gsum = 0.0f;
        float sa0 = 0.f, sa1 = 0.f, sa2 = 0.f, sa3 = 0.f;
        #pragma unroll
        for (int q = 0; q < NW; ++q) {
            gsum += red_es[q * 8 + grp];
            const float4 rm =
                *reinterpret_cast<const float4*>(&red_m[(q * 8 + grp) * 4]);
            sa0 += rm.x; sa1 += rm.y; sa2 += rm.z; sa3 += rm.w;
        }
        __syncthreads();   // reads done before next iteration's writes

        const float cinv = 1.0f / gsum;
        vv[0] = sa0 * cinv; vv[1] = sa1 * cinv;
        vv[2] = sa2 * cinv; vv[3] = sa3 * cinv;
        float s2 = fmaf(vv[0], vv[0], fmaf(vv[1], vv[1],
                   fmaf(vv[2], vv[2], vv[3] * vv[3])));
        s2 += __shfl_xor(s2, 2);   // combine the 4 m-quarters (same bl)
        s2 += __shfl_xor(s2, 4);
        const float scale = (s2 / (1.0f + s2)) * rsqrtf(s2 + 1e-8f);
        vv[0] *= scale; vv[1] *= scale; vv[2] *= scale; vv[3] *= scale;

        // logit update: a = sum_m v[m]*uh[i][m]; mq partners via masks 2,4
        if (it < ITERS - 1) {
            #pragma unroll
            for (int r = 0; r < NTILE; ++r) {
                float a = fmaf(vv[0], uh[r][0], fmaf(vv[1], uh[r][1],
                          fmaf(vv[2], uh[r][2], vv[3] * uh[r][3])));
                a += __shfl_xor(a, 2);
                a += __shfl_xor(a, 4);
                blog[r] += a;
            }
        }
    }

    // ---- write v[b0+bl, j, mq*4 .. mq*4+3] ----
    if (tid < 8) {
        float4* op = reinterpret_cast<float4*>(
            out + ((size_t)(b0 + bl) * OUT_CAPS + j) * OUT_D + mq * 4);
        *op = make_float4(vv[0], vv[1], vv[2], vv[3]);
    }
}

extern "C" void kernel_launch(void* const* d_in, const int* in_sizes, int n_in,
                              void* d_out, int out_size, void* d_ws, size_t ws_size,
                              hipStream_t stream) {
    const float* u = (const float*)d_in[0];   // [128, 1152, 8]
    const float* w = (const float*)d_in[1];   // [1152, 32, 8, 16]
    float* out     = (float*)d_out;           // [128, 32, 16]
    (void)in_sizes; (void)n_in; (void)out_size; (void)d_ws; (void)ws_size;

    dim3 grid(OUT_CAPS * (B_SZ / G));   // 32 j x 64 batch-pairs = 2048 blocks
    dim3 block(THREADS);                // 1024 threads = 16 waves
    hipLaunchKernelGGL(caps_route, grid, block, 0, stream, u, w, out);
}